// Round 8
// baseline (2073.521 us; speedup 1.0000x reference)
//
#include <hip/hip_runtime.h>

// ---------------------------------------------------------------------------
// HypergraphNeuralCDE: y' = tanh(conv(y)) . dX/dt, RK4 (2 substeps/interval)
// Round 7: front-load all gather-independent global loads in k_drift_f
// (Wt frags, bias, epilogue y/acc float4s) so they overlap the gather chain.
// ---------------------------------------------------------------------------

typedef __attribute__((ext_vector_type(8))) short bfrag8;   // 8 bf16
typedef __attribute__((ext_vector_type(4))) float f32x4;

__device__ __forceinline__ float bf2f(ushort u) {
  union { uint i; float f; } v; v.i = (uint)u << 16; return v.f;
}
__device__ __forceinline__ ushort f2bf(float f) {
  union { uint i; float f; } v; v.f = f;
  uint r = v.i + 0x7fff + ((v.i >> 16) & 1);   // RNE
  return (ushort)(r >> 16);
}
__device__ __forceinline__ uint pack2(float lo, float hi) {
  return ((uint)f2bf(hi) << 16) | (uint)f2bf(lo);
}

// ---------------- CSR construction + one-time prep --------------------------
__global__ __launch_bounds__(256) void k_count(const int* __restrict__ node_idx,
                                               const int* __restrict__ edge_idx,
                                               int* __restrict__ cnt_e,
                                               int* __restrict__ cnt_n, int nnz,
                                               const float* __restrict__ W,
                                               const float* __restrict__ y0,
                                               ushort* __restrict__ Wt,
                                               ushort* __restrict__ y0bf,
                                               float* __restrict__ out,
                                               int nW, int nY) {
  int j = blockIdx.x * 256 + threadIdx.x;
  if (j < nnz) {
    atomicAdd(&cnt_e[edge_idx[j]], 1);
    atomicAdd(&cnt_n[node_idx[j]], 1);
  }
  int stride = gridDim.x * 256;
  for (int i = j; i < nY; i += stride) {
    float v = y0[i];
    y0bf[i] = f2bf(v);
    out[i] = v;                            // out[0] = y0 (folded copy)
  }
  for (int i = j; i < nW; i += stride) {
    int k = i >> 9, c = i & 511;           // W is (64,512) row-major
    Wt[c * 64 + k] = f2bf(W[i]);
  }
}

// two independent scans in one dispatch: block 0 -> edges, block 1 -> nodes
__global__ __launch_bounds__(1024) void k_scan2(const int* __restrict__ cnt_e,
                                                int* __restrict__ off_e,
                                                int* __restrict__ cur_e, int m,
                                                const int* __restrict__ cnt_n,
                                                int* __restrict__ off_n,
                                                int* __restrict__ cur_n, int n) {
  const int* cnt = (blockIdx.x == 0) ? cnt_e : cnt_n;
  int* off = (blockIdx.x == 0) ? off_e : off_n;
  int* cur = (blockIdx.x == 0) ? cur_e : cur_n;
  int len = (blockIdx.x == 0) ? m : n;
  __shared__ int sd[1024];
  __shared__ int s_run;
  if (threadIdx.x == 0) s_run = 0;
  __syncthreads();
  for (int base = 0; base < len; base += 1024) {
    int i = base + threadIdx.x;
    int v = (i < len) ? cnt[i] : 0;
    sd[threadIdx.x] = v;
    __syncthreads();
    for (int ofs = 1; ofs < 1024; ofs <<= 1) {
      int tv = (threadIdx.x >= ofs) ? sd[threadIdx.x - ofs] : 0;
      __syncthreads();
      sd[threadIdx.x] += tv;
      __syncthreads();
    }
    int run = s_run;
    if (i < len) {
      int excl = run + sd[threadIdx.x] - v;
      off[i] = excl;
      cur[i] = excl;
    }
    __syncthreads();
    if (threadIdx.x == 1023) s_run = run + sd[1023];
    __syncthreads();
  }
  if (threadIdx.x == 0) off[len] = s_run;
}

// fill + invdeg folded
__global__ __launch_bounds__(256) void k_fill(const int* __restrict__ node_idx,
                                              const int* __restrict__ edge_idx,
                                              int* __restrict__ cur_e,
                                              int* __restrict__ cur_n,
                                              int* __restrict__ csr_e,
                                              int* __restrict__ csr_n, int nnz,
                                              const int* __restrict__ cnt_e,
                                              const int* __restrict__ cnt_n,
                                              float* __restrict__ inv_e,
                                              float* __restrict__ inv_n,
                                              int m, int n) {
  int j = blockIdx.x * 256 + threadIdx.x;
  if (j < nnz) {
    int v = node_idx[j], e = edge_idx[j];
    int pe = atomicAdd(&cur_e[e], 1);
    csr_e[pe] = v;
    int pn = atomicAdd(&cur_n[v], 1);
    csr_n[pn] = e;
  }
  if (j < m) inv_e[j] = 1.f / (float)max(cnt_e[j], 1);
  if (j < n) inv_n[j] = 1.f / (float)max(cnt_n[j], 1);
}

// ---------------- 16-entry unrolled segment accumulate ----------------------
__device__ __forceinline__ void seg_gather(const uint* __restrict__ src,
                                           const int* __restrict__ csr,
                                           int p, int pe, int cp,
                                           float& A0, float& A1) {
  float a0 = 0.f, a1 = 0.f, b0 = 0.f, b1 = 0.f;
  for (; p + 14 < pe; p += 16) {
    int r0 = csr[p],      r1 = csr[p + 2],  r2 = csr[p + 4],  r3 = csr[p + 6];
    int r4 = csr[p + 8],  r5 = csr[p + 10], r6 = csr[p + 12], r7 = csr[p + 14];
    uint v0 = src[(size_t)r0 * 32 + cp];
    uint v1 = src[(size_t)r1 * 32 + cp];
    uint v2 = src[(size_t)r2 * 32 + cp];
    uint v3 = src[(size_t)r3 * 32 + cp];
    uint v4 = src[(size_t)r4 * 32 + cp];
    uint v5 = src[(size_t)r5 * 32 + cp];
    uint v6 = src[(size_t)r6 * 32 + cp];
    uint v7 = src[(size_t)r7 * 32 + cp];
    a0 += bf2f((ushort)(v0 & 0xffff)) + bf2f((ushort)(v2 & 0xffff))
        + bf2f((ushort)(v4 & 0xffff)) + bf2f((ushort)(v6 & 0xffff));
    a1 += bf2f((ushort)(v0 >> 16)) + bf2f((ushort)(v2 >> 16))
        + bf2f((ushort)(v4 >> 16)) + bf2f((ushort)(v6 >> 16));
    b0 += bf2f((ushort)(v1 & 0xffff)) + bf2f((ushort)(v3 & 0xffff))
        + bf2f((ushort)(v5 & 0xffff)) + bf2f((ushort)(v7 & 0xffff));
    b1 += bf2f((ushort)(v1 >> 16)) + bf2f((ushort)(v3 >> 16))
        + bf2f((ushort)(v5 >> 16)) + bf2f((ushort)(v7 >> 16));
  }
  if (p + 6 < pe) {
    int r0 = csr[p], r1 = csr[p + 2], r2 = csr[p + 4], r3 = csr[p + 6];
    uint v0 = src[(size_t)r0 * 32 + cp];
    uint v1 = src[(size_t)r1 * 32 + cp];
    uint v2 = src[(size_t)r2 * 32 + cp];
    uint v3 = src[(size_t)r3 * 32 + cp];
    a0 += bf2f((ushort)(v0 & 0xffff)) + bf2f((ushort)(v2 & 0xffff));
    a1 += bf2f((ushort)(v0 >> 16)) + bf2f((ushort)(v2 >> 16));
    b0 += bf2f((ushort)(v1 & 0xffff)) + bf2f((ushort)(v3 & 0xffff));
    b1 += bf2f((ushort)(v1 >> 16)) + bf2f((ushort)(v3 >> 16));
    p += 8;
  }
  if (p + 2 < pe) {
    int r0 = csr[p], r1 = csr[p + 2];
    uint v0 = src[(size_t)r0 * 32 + cp];
    uint v1 = src[(size_t)r1 * 32 + cp];
    a0 += bf2f((ushort)(v0 & 0xffff));
    a1 += bf2f((ushort)(v0 >> 16));
    b0 += bf2f((ushort)(v1 & 0xffff));
    b1 += bf2f((ushort)(v1 >> 16));
    p += 4;
  }
  if (p < pe) {
    uint v0 = src[(size_t)csr[p] * 32 + cp];
    a0 += bf2f((ushort)(v0 & 0xffff));
    a1 += bf2f((ushort)(v0 >> 16));
  }
  A0 = a0 + b0;
  A1 = a1 + b1;
}

// ---------------- K1: edge mean, bf16 in/out --------------------------------
__global__ __launch_bounds__(256) void k_seg_mean_bf(const uint* __restrict__ src,
                                                     const int* __restrict__ off,
                                                     const int* __restrict__ csr,
                                                     const float* __restrict__ invdeg,
                                                     uint* __restrict__ dst,
                                                     int nseg) {
  int gid = blockIdx.x * 256 + threadIdx.x;
  int seg = gid >> 6;
  if (seg >= nseg) return;
  int lane = gid & 63;
  int half = lane >> 5;
  int cp = lane & 31;
  float sc = invdeg[seg];
  float a0, a1;
  seg_gather(src, csr, off[seg] + half, off[seg + 1], cp, a0, a1);
  a0 += __shfl_xor(a0, 32);
  a1 += __shfl_xor(a1, 32);
  if (half == 0)
    dst[(size_t)seg * 32 + cp] = pack2(a0 * sc, a1 * sc);
}

// ---------------- K2: fused node-mean + MFMA + tanh/contract + RK4 ----------
// 16-node tile, 1024 threads = 16 waves; wave w gathers node nodebase+w and
// covers raw cols [32w, 32w+32). ALL gather-independent loads issued first.
__global__ __launch_bounds__(1024, 8) void k_drift_f(
    const uint* __restrict__ e_bf,
    const int* __restrict__ off_n, const int* __restrict__ csr_n,
    const float* __restrict__ invdeg_n,
    const ushort* __restrict__ Wt, const float* __restrict__ bvec,
    const float* __restrict__ controls, const float* __restrict__ ts,
    const float* __restrict__ y_base, float* __restrict__ acc_out,
    uint* __restrict__ ybf,
    int t, int stage, int substep, int n) {
  __shared__ uint aggs[16][36];   // row stride 144 B (16B-aligned)
  __shared__ float Us[16][8];
  __shared__ float kvs[16][68];

  const int tid = threadIdx.x;
  const int w = tid >> 6;        // wave 0..15
  const int lane = tid & 63;
  const int half = lane >> 5;
  const int cp = lane & 31;
  const int nodebase = blockIdx.x * 16;

  // ===== 1. issue every gather-independent global load up front =============
  // (a) B fragments + bias for this wave's two MFMA columns (L2-resident)
  const int colA = w * 32 + (lane & 15);
  const int colB = colA + 16;
  const ushort* wbA = Wt + (size_t)colA * 64 + (lane >> 4) * 8;
  const ushort* wbB = Wt + (size_t)colB * 64 + (lane >> 4) * 8;
  bfrag8 bA0 = *reinterpret_cast<const bfrag8*>(wbA);
  bfrag8 bA1 = *reinterpret_cast<const bfrag8*>(wbA + 32);
  bfrag8 bB0 = *reinterpret_cast<const bfrag8*>(wbB);
  bfrag8 bB1 = *reinterpret_cast<const bfrag8*>(wbB + 32);
  float bbA = bvec[colA];
  float bbB = bvec[colB];

  // (b) epilogue RK4 operands (threads < 256): y_base / acc_out float4
  float4 ya = make_float4(0.f, 0.f, 0.f, 0.f);
  float4 pa = ya;
  const int nl4 = tid >> 4;
  const int f0 = (tid & 15) * 4;
  const size_t o4 = (size_t)(nodebase + nl4) * 64 + f0;
  if (tid < 256) {
    ya = *reinterpret_cast<const float4*>(y_base + o4);
    pa = (stage == 1) ? ya : *reinterpret_cast<const float4*>(acc_out + o4);
  }

  // (c) scalar time coefficients + control derivative (threads < 128)
  float t0v = ts[t], t1v = ts[t + 1];
  float h = t1v - t0v;
  float hs = 0.5f * h;
  float soff = (stage == 1) ? 0.f : (stage == 4) ? 1.f : 0.5f;
  float s = ((float)substep + soff) * 0.5f;
  float s2 = s * s;
  float cx0 = (6.f * s2 - 6.f * s) / h;
  float cd0 = 3.f * s2 - 4.f * s + 1.f;
  float cx1 = (-6.f * s2 + 6.f * s) / h;
  float cd1 = 3.f * s2 - 2.f * s;
  float a_m1, a_0, a_p1;
  if (t == 0) {
    a_m1 = 0.f;
    a_0 = cx0 - cd1 / h - cd0 / h;
    a_p1 = cx1 + cd1 / h + cd0 / h;
  } else {
    float hm = t0v - ts[t - 1];
    a_m1 = -cd0 / hm;
    a_0 = cx0 - cd1 / h + cd0 / hm;
    a_p1 = cx1 + cd1 / h;
  }
  int tm1 = (t > 0) ? t - 1 : 0;
  float wk = ((stage == 2 || stage == 3) ? 2.f : 1.f) * hs * (1.f / 6.f);
  float cst = (stage == 3) ? hs : 0.5f * hs;

  if (tid < 128) {
    int nl = tid >> 3, ci = tid & 7;
    size_t bi = (size_t)(nodebase + nl) * 8 + ci;
    float c0 = controls[(size_t)t * n * 8 + bi];
    float cp1 = controls[(size_t)(t + 1) * n * 8 + bi];
    float cm1 = controls[(size_t)tm1 * n * 8 + bi];
    Us[nl][ci] = a_m1 * cm1 + a_0 * c0 + a_p1 * cp1;
  }

  // ===== 2. node-hop gather: wave w -> node nodebase + w ====================
  {
    int gnode = nodebase + w;
    float sc = invdeg_n[gnode];
    float a0, a1;
    seg_gather(e_bf, csr_n, off_n[gnode] + half, off_n[gnode + 1], cp, a0, a1);
    a0 += __shfl_xor(a0, 32);
    a1 += __shfl_xor(a1, 32);
    if (half == 0) aggs[w][cp] = pack2(a0 * sc, a1 * sc);
  }
  __syncthreads();

  // ===== 3. MFMA + tanh + contraction (fragments already in registers) ======
  int arow = lane & 15;
  int kof4 = (lane >> 4) * 4;
  bfrag8 af0 = *reinterpret_cast<const bfrag8*>(&aggs[arow][kof4]);
  bfrag8 af1 = *reinterpret_cast<const bfrag8*>(&aggs[arow][kof4 + 16]);
  int ci = lane & 7, g8 = (lane >> 3) & 1;
  int rbase = (lane >> 4) * 4;
  float u_r[4];
  #pragma unroll
  for (int r = 0; r < 4; ++r) u_r[r] = Us[rbase + r][ci];

  {
    f32x4 accA = (f32x4){0.f, 0.f, 0.f, 0.f};
    accA = __builtin_amdgcn_mfma_f32_16x16x32_bf16(af0, bA0, accA, 0, 0, 0);
    accA = __builtin_amdgcn_mfma_f32_16x16x32_bf16(af1, bA1, accA, 0, 0, 0);
    f32x4 accB = (f32x4){0.f, 0.f, 0.f, 0.f};
    accB = __builtin_amdgcn_mfma_f32_16x16x32_bf16(af0, bB0, accB, 0, 0, 0);
    accB = __builtin_amdgcn_mfma_f32_16x16x32_bf16(af1, bB1, accB, 0, 0, 0);
    #pragma unroll
    for (int r = 0; r < 4; ++r) {
      float xA = accA[r] + bbA;
      float thA = 1.f - 2.f / (__expf(2.f * xA) + 1.f);  // tanh, NaN-safe
      float vA = thA * u_r[r];
      vA += __shfl_xor(vA, 1);
      vA += __shfl_xor(vA, 2);
      vA += __shfl_xor(vA, 4);
      float xB = accB[r] + bbB;
      float thB = 1.f - 2.f / (__expf(2.f * xB) + 1.f);
      float vB = thB * u_r[r];
      vB += __shfl_xor(vB, 1);
      vB += __shfl_xor(vB, 2);
      vB += __shfl_xor(vB, 4);
      if (ci == 0) {
        kvs[rbase + r][w * 4 + g8] = vA;
        kvs[rbase + r][w * 4 + 2 + g8] = vB;
      }
    }
  }
  __syncthreads();

  // ===== 4. RK4 update (operands prefetched in step 1) ======================
  if (tid < 256) {
    float4 kv = *reinterpret_cast<float4*>(&kvs[nl4][f0]);
    float4 na;
    na.x = pa.x + wk * kv.x; na.y = pa.y + wk * kv.y;
    na.z = pa.z + wk * kv.z; na.w = pa.w + wk * kv.w;
    *reinterpret_cast<float4*>(acc_out + o4) = na;
    float4 sa;
    if (stage < 4) {
      sa.x = ya.x + cst * kv.x; sa.y = ya.y + cst * kv.y;
      sa.z = ya.z + cst * kv.z; sa.w = ya.w + cst * kv.w;
    } else sa = na;
    uint2 pk;
    pk.x = pack2(sa.x, sa.y);
    pk.y = pack2(sa.z, sa.w);
    *reinterpret_cast<uint2*>(ybf + ((size_t)(nodebase + nl4) * 32 + f0 / 2)) = pk;
  }
}

// ---------------------------------------------------------------------------
extern "C" void kernel_launch(void* const* d_in, const int* in_sizes, int n_in,
                              void* d_out, int out_size, void* d_ws, size_t ws_size,
                              hipStream_t stream) {
  const float* y0 = (const float*)d_in[0];
  const float* ts = (const float*)d_in[1];
  const float* controls = (const float*)d_in[2];
  const float* W = (const float*)d_in[3];
  const float* bvec = (const float*)d_in[4];
  const int* node_idx = (const int*)d_in[5];
  const int* edge_idx = (const int*)d_in[6];

  const int d = 64;
  const int n = in_sizes[0] / d;         // 20000
  const int T = in_sizes[1];             // 8
  const int nnz = in_sizes[5];           // 320000
  const int m = 5000;                    // num_edges (fixed by setup_inputs)

  char* p = (char*)d_ws;
  auto carve = [&](size_t bytes) {
    char* r = p;
    p += (bytes + 255) & ~(size_t)255;
    return r;
  };
  int* cnt = (int*)carve((size_t)(m + n) * 4);   // cnt_e | cnt_n contiguous
  int* cnt_e = cnt;
  int* cnt_n = cnt + m;
  int* off_e = (int*)carve((size_t)(m + 1) * 4);
  int* cur_e = (int*)carve((size_t)m * 4);
  int* off_n = (int*)carve((size_t)(n + 1) * 4);
  int* cur_n = (int*)carve((size_t)n * 4);
  int* csr_e = (int*)carve((size_t)nnz * 4);
  int* csr_n = (int*)carve((size_t)nnz * 4);
  float* invdeg_e = (float*)carve((size_t)m * 4);
  float* invdeg_n = (float*)carve((size_t)n * 4);
  ushort* Wt = (ushort*)carve((size_t)512 * 64 * 2);
  ushort* ybf = (ushort*)carve((size_t)n * d * 2);
  ushort* e_bf = (ushort*)carve((size_t)m * d * 2);
  float* y_mid = (float*)carve((size_t)n * d * 4);

  float* out = (float*)d_out;

  hipMemsetAsync(cnt, 0, (size_t)(m + n) * 4, stream);
  k_count<<<(nnz + 255) / 256, 256, 0, stream>>>(node_idx, edge_idx, cnt_e, cnt_n,
                                                 nnz, W, y0, Wt, ybf, out,
                                                 64 * 512, n * d);
  k_scan2<<<2, 1024, 0, stream>>>(cnt_e, off_e, cur_e, m, cnt_n, off_n, cur_n, n);
  k_fill<<<(nnz + 255) / 256, 256, 0, stream>>>(node_idx, edge_idx, cur_e, cur_n,
                                                csr_e, csr_n, nnz, cnt_e, cnt_n,
                                                invdeg_e, invdeg_n, m, n);

  const int gE = (m * 64 + 255) / 256;   // 1250
  const int gT = n / 16;                 // 1250 (n = 20000)

  for (int t = 0; t < T - 1; ++t) {
    float* yout_i = out + (size_t)(t + 1) * n * d;
    for (int sub = 0; sub < 2; ++sub) {
      const float* yb = (sub == 0) ? (out + (size_t)t * n * d) : y_mid;
      float* accp = (sub == 0) ? y_mid : yout_i;
      for (int st = 1; st <= 4; ++st) {
        k_seg_mean_bf<<<gE, 256, 0, stream>>>((const uint*)ybf, off_e, csr_e,
                                              invdeg_e, (uint*)e_bf, m);
        k_drift_f<<<gT, 1024, 0, stream>>>((const uint*)e_bf, off_n, csr_n,
                                           invdeg_n, Wt, bvec, controls, ts,
                                           yb, accp, (uint*)ybf, t, st, sub, n);
      }
    }
  }
}

// Round 10
// 1981.184 us; speedup vs baseline: 1.0466x; 1.0466x over previous
//
#include <hip/hip_runtime.h>

// ---------------------------------------------------------------------------
// HypergraphNeuralCDE: y' = tanh(conv(y)) . dX/dt, RK4 (2 substeps/interval)
// Round 9: shfl-staged gathers FIXED for wave-uniformity. All __shfl calls
// sit in loops whose bounds depend only on wave-uniform cnt (round 8's
// per-half trip counts made shfl read inactive lanes -> undefined -> wrong
// sums). Tail is predicated on the load, not the shfl.
// ---------------------------------------------------------------------------

typedef __attribute__((ext_vector_type(8))) short bfrag8;   // 8 bf16
typedef __attribute__((ext_vector_type(4))) float f32x4;

__device__ __forceinline__ float bf2f(ushort u) {
  union { uint i; float f; } v; v.i = (uint)u << 16; return v.f;
}
__device__ __forceinline__ ushort f2bf(float f) {
  union { uint i; float f; } v; v.f = f;
  uint r = v.i + 0x7fff + ((v.i >> 16) & 1);   // RNE
  return (ushort)(r >> 16);
}
__device__ __forceinline__ uint pack2(float lo, float hi) {
  return ((uint)f2bf(hi) << 16) | (uint)f2bf(lo);
}

// ---------------- CSR construction + one-time prep --------------------------
__global__ __launch_bounds__(256) void k_count(const int* __restrict__ node_idx,
                                               const int* __restrict__ edge_idx,
                                               int* __restrict__ cnt_e,
                                               int* __restrict__ cnt_n, int nnz,
                                               const float* __restrict__ W,
                                               const float* __restrict__ y0,
                                               ushort* __restrict__ Wt,
                                               ushort* __restrict__ y0bf,
                                               float* __restrict__ out,
                                               int nW, int nY) {
  int j = blockIdx.x * 256 + threadIdx.x;
  if (j < nnz) {
    atomicAdd(&cnt_e[edge_idx[j]], 1);
    atomicAdd(&cnt_n[node_idx[j]], 1);
  }
  int stride = gridDim.x * 256;
  for (int i = j; i < nY; i += stride) {
    float v = y0[i];
    y0bf[i] = f2bf(v);
    out[i] = v;                            // out[0] = y0 (folded copy)
  }
  for (int i = j; i < nW; i += stride) {
    int k = i >> 9, c = i & 511;           // W is (64,512) row-major
    Wt[c * 64 + k] = f2bf(W[i]);
  }
}

// two independent scans in one dispatch: block 0 -> edges, block 1 -> nodes
__global__ __launch_bounds__(1024) void k_scan2(const int* __restrict__ cnt_e,
                                                int* __restrict__ off_e,
                                                int* __restrict__ cur_e, int m,
                                                const int* __restrict__ cnt_n,
                                                int* __restrict__ off_n,
                                                int* __restrict__ cur_n, int n) {
  const int* cnt = (blockIdx.x == 0) ? cnt_e : cnt_n;
  int* off = (blockIdx.x == 0) ? off_e : off_n;
  int* cur = (blockIdx.x == 0) ? cur_e : cur_n;
  int len = (blockIdx.x == 0) ? m : n;
  __shared__ int sd[1024];
  __shared__ int s_run;
  if (threadIdx.x == 0) s_run = 0;
  __syncthreads();
  for (int base = 0; base < len; base += 1024) {
    int i = base + threadIdx.x;
    int v = (i < len) ? cnt[i] : 0;
    sd[threadIdx.x] = v;
    __syncthreads();
    for (int ofs = 1; ofs < 1024; ofs <<= 1) {
      int tv = (threadIdx.x >= ofs) ? sd[threadIdx.x - ofs] : 0;
      __syncthreads();
      sd[threadIdx.x] += tv;
      __syncthreads();
    }
    int run = s_run;
    if (i < len) {
      int excl = run + sd[threadIdx.x] - v;
      off[i] = excl;
      cur[i] = excl;
    }
    __syncthreads();
    if (threadIdx.x == 1023) s_run = run + sd[1023];
    __syncthreads();
  }
  if (threadIdx.x == 0) off[len] = s_run;
}

// fill + invdeg folded
__global__ __launch_bounds__(256) void k_fill(const int* __restrict__ node_idx,
                                              const int* __restrict__ edge_idx,
                                              int* __restrict__ cur_e,
                                              int* __restrict__ cur_n,
                                              int* __restrict__ csr_e,
                                              int* __restrict__ csr_n, int nnz,
                                              const int* __restrict__ cnt_e,
                                              const int* __restrict__ cnt_n,
                                              float* __restrict__ inv_e,
                                              float* __restrict__ inv_n,
                                              int m, int n) {
  int j = blockIdx.x * 256 + threadIdx.x;
  if (j < nnz) {
    int v = node_idx[j], e = edge_idx[j];
    int pe = atomicAdd(&cur_e[e], 1);
    csr_e[pe] = v;
    int pn = atomicAdd(&cur_n[v], 1);
    csr_n[pn] = e;
  }
  if (j < m) inv_e[j] = 1.f / (float)max(cnt_e[j], 1);
  if (j < n) inv_n[j] = 1.f / (float)max(cnt_n[j], 1);
}

// ---------------- wave-uniform shfl-staged segment accumulate ---------------
// Per wave: load up to 64 CSR indices coalesced (lane i -> csr[p0+base+i]),
// broadcast via __shfl. Half h accumulates entries h, h+2, ... ALL shfls sit
// at wave-uniform program points (loop bounds depend only on cnt); only the
// tail's load is predicated (divergent loads are safe, divergent shfls NOT).
__device__ __forceinline__ void seg_gather(const uint* __restrict__ src,
                                           const int* __restrict__ csr,
                                           int p0, int pe, int lane,
                                           float& A0, float& A1) {
  const int half = lane >> 5;
  const int cp = lane & 31;
  const int nent = pe - p0;
  float a0 = 0.f, a1 = 0.f, b0 = 0.f, b1 = 0.f;
  for (int base = 0; base < nent; base += 64) {
    int cnt = nent - base;
    cnt = (cnt > 64) ? 64 : cnt;
    int myidx = (lane < cnt) ? csr[p0 + base + lane] : 0;
    int j = 0;
    // full blocks: entries half+2j .. half+2j+14 valid for BOTH halves
    for (; 2 * j + 15 < cnt; j += 8) {
      int e = half + 2 * j;
      int r0 = __shfl(myidx, e);
      int r1 = __shfl(myidx, e + 2);
      int r2 = __shfl(myidx, e + 4);
      int r3 = __shfl(myidx, e + 6);
      int r4 = __shfl(myidx, e + 8);
      int r5 = __shfl(myidx, e + 10);
      int r6 = __shfl(myidx, e + 12);
      int r7 = __shfl(myidx, e + 14);
      uint v0 = src[(size_t)r0 * 32 + cp];
      uint v1 = src[(size_t)r1 * 32 + cp];
      uint v2 = src[(size_t)r2 * 32 + cp];
      uint v3 = src[(size_t)r3 * 32 + cp];
      uint v4 = src[(size_t)r4 * 32 + cp];
      uint v5 = src[(size_t)r5 * 32 + cp];
      uint v6 = src[(size_t)r6 * 32 + cp];
      uint v7 = src[(size_t)r7 * 32 + cp];
      a0 += bf2f((ushort)(v0 & 0xffff)) + bf2f((ushort)(v2 & 0xffff))
          + bf2f((ushort)(v4 & 0xffff)) + bf2f((ushort)(v6 & 0xffff));
      a1 += bf2f((ushort)(v0 >> 16)) + bf2f((ushort)(v2 >> 16))
          + bf2f((ushort)(v4 >> 16)) + bf2f((ushort)(v6 >> 16));
      b0 += bf2f((ushort)(v1 & 0xffff)) + bf2f((ushort)(v3 & 0xffff))
          + bf2f((ushort)(v5 & 0xffff)) + bf2f((ushort)(v7 & 0xffff));
      b1 += bf2f((ushort)(v1 >> 16)) + bf2f((ushort)(v3 >> 16))
          + bf2f((ushort)(v5 >> 16)) + bf2f((ushort)(v7 >> 16));
    }
    // predicated tail (<=8 iters), wave-uniform bound: 2j < cnt
    for (; 2 * j < cnt; ++j) {
      int e = half + 2 * j;
      int es = (e < 63) ? e : 63;        // clamp shfl source into [0,63]
      int r = __shfl(myidx, es);         // uniform program point, all active
      if (e < cnt) {                     // divergence only around the load
        uint v = src[(size_t)r * 32 + cp];
        a0 += bf2f((ushort)(v & 0xffff));
        a1 += bf2f((ushort)(v >> 16));
      }
    }
  }
  A0 = a0 + b0;
  A1 = a1 + b1;
}

// ---------------- K1: edge mean, bf16 in/out --------------------------------
__global__ __launch_bounds__(256) void k_seg_mean_bf(const uint* __restrict__ src,
                                                     const int* __restrict__ off,
                                                     const int* __restrict__ csr,
                                                     const float* __restrict__ invdeg,
                                                     uint* __restrict__ dst,
                                                     int nseg) {
  int gid = blockIdx.x * 256 + threadIdx.x;
  int seg = gid >> 6;
  if (seg >= nseg) return;
  int lane = gid & 63;
  float sc = invdeg[seg];
  float a0, a1;
  seg_gather(src, csr, off[seg], off[seg + 1], lane, a0, a1);
  a0 += __shfl_xor(a0, 32);
  a1 += __shfl_xor(a1, 32);
  if ((lane >> 5) == 0)
    dst[(size_t)seg * 32 + (lane & 31)] = pack2(a0 * sc, a1 * sc);
}

// ---------------- K2: fused node-mean + MFMA + tanh/contract + RK4 ----------
// 16-node tile, 1024 threads = 16 waves; wave w gathers node nodebase+w and
// covers raw cols [32w, 32w+32). (round-6 structure, fixed shfl-staged gather)
__global__ __launch_bounds__(1024, 8) void k_drift_f(
    const uint* __restrict__ e_bf,
    const int* __restrict__ off_n, const int* __restrict__ csr_n,
    const float* __restrict__ invdeg_n,
    const ushort* __restrict__ Wt, const float* __restrict__ bvec,
    const float* __restrict__ controls, const float* __restrict__ ts,
    const float* __restrict__ y_base, float* __restrict__ acc_out,
    uint* __restrict__ ybf,
    int t, int stage, int substep, int n) {
  __shared__ uint aggs[16][36];   // row stride 144 B (16B-aligned)
  __shared__ float Us[16][8];
  __shared__ float kvs[16][68];

  const int tid = threadIdx.x;
  const int w = tid >> 6;        // wave 0..15
  const int lane = tid & 63;
  const int cp = lane & 31;
  const int nodebase = blockIdx.x * 16;

  // --- scalar time coefficients (uniform -> SGPR) ---
  float t0v = ts[t], t1v = ts[t + 1];
  float h = t1v - t0v;
  float hs = 0.5f * h;
  float soff = (stage == 1) ? 0.f : (stage == 4) ? 1.f : 0.5f;
  float s = ((float)substep + soff) * 0.5f;
  float s2 = s * s;
  float cx0 = (6.f * s2 - 6.f * s) / h;
  float cd0 = 3.f * s2 - 4.f * s + 1.f;
  float cx1 = (-6.f * s2 + 6.f * s) / h;
  float cd1 = 3.f * s2 - 2.f * s;
  float a_m1, a_0, a_p1;
  if (t == 0) {
    a_m1 = 0.f;
    a_0 = cx0 - cd1 / h - cd0 / h;
    a_p1 = cx1 + cd1 / h + cd0 / h;
  } else {
    float hm = t0v - ts[t - 1];
    a_m1 = -cd0 / hm;
    a_0 = cx0 - cd1 / h + cd0 / hm;
    a_p1 = cx1 + cd1 / h;
  }
  int tm1 = (t > 0) ? t - 1 : 0;
  float wk = ((stage == 2 || stage == 3) ? 2.f : 1.f) * hs * (1.f / 6.f);
  float cst = (stage == 3) ? hs : 0.5f * hs;

  // --- control derivative for the tile's 16 nodes (first 128 threads) ---
  if (tid < 128) {
    int nl = tid >> 3, ci = tid & 7;
    size_t bi = (size_t)(nodebase + nl) * 8 + ci;
    float c0 = controls[(size_t)t * n * 8 + bi];
    float cp1 = controls[(size_t)(t + 1) * n * 8 + bi];
    float cm1 = controls[(size_t)tm1 * n * 8 + bi];
    Us[nl][ci] = a_m1 * cm1 + a_0 * c0 + a_p1 * cp1;
  }

  // --- node-hop gather: wave w -> node nodebase + w ---
  {
    int gnode = nodebase + w;
    float sc = invdeg_n[gnode];
    float a0, a1;
    seg_gather(e_bf, csr_n, off_n[gnode], off_n[gnode + 1], lane, a0, a1);
    a0 += __shfl_xor(a0, 32);
    a1 += __shfl_xor(a1, 32);
    if ((lane >> 5) == 0) aggs[w][cp] = pack2(a0 * sc, a1 * sc);
  }
  __syncthreads();

  // --- MFMA: wave w covers raw cols [32w, 32w+32) ---
  int arow = lane & 15;
  int kof4 = (lane >> 4) * 4;    // uint offset into aggs row
  bfrag8 af0 = *reinterpret_cast<const bfrag8*>(&aggs[arow][kof4]);
  bfrag8 af1 = *reinterpret_cast<const bfrag8*>(&aggs[arow][kof4 + 16]);
  int ci = lane & 7, g8 = (lane >> 3) & 1;
  int rbase = (lane >> 4) * 4;
  float u_r[4];
  #pragma unroll
  for (int r = 0; r < 4; ++r) u_r[r] = Us[rbase + r][ci];

  #pragma unroll
  for (int ctl = 0; ctl < 2; ++ctl) {
    int col = w * 32 + ctl * 16 + (lane & 15);
    const ushort* wb = Wt + (size_t)col * 64 + (lane >> 4) * 8;
    bfrag8 b0 = *reinterpret_cast<const bfrag8*>(wb);
    bfrag8 b1 = *reinterpret_cast<const bfrag8*>(wb + 32);
    f32x4 acc = (f32x4){0.f, 0.f, 0.f, 0.f};
    acc = __builtin_amdgcn_mfma_f32_16x16x32_bf16(af0, b0, acc, 0, 0, 0);
    acc = __builtin_amdgcn_mfma_f32_16x16x32_bf16(af1, b1, acc, 0, 0, 0);
    float bb = bvec[col];
    int ddl = w * 4 + ctl * 2 + g8;
    #pragma unroll
    for (int r = 0; r < 4; ++r) {
      float x = acc[r] + bb;
      float th = 1.f - 2.f / (__expf(2.f * x) + 1.f);  // tanh, NaN-safe
      float v = th * u_r[r];
      v += __shfl_xor(v, 1);
      v += __shfl_xor(v, 2);
      v += __shfl_xor(v, 4);
      if (ci == 0) kvs[rbase + r][ddl] = v;
    }
  }
  __syncthreads();

  // --- RK4 update: first 256 threads, node tid>>4, feats (tid&15)*4 .. +4 ---
  if (tid < 256) {
    int nl4 = tid >> 4;
    int f0 = (tid & 15) * 4;
    size_t o4 = (size_t)(nodebase + nl4) * 64 + f0;
    float4 kv = *reinterpret_cast<float4*>(&kvs[nl4][f0]);
    float4 ya = *reinterpret_cast<const float4*>(y_base + o4);
    float4 pa = ya;
    if (stage != 1) pa = *reinterpret_cast<const float4*>(acc_out + o4);
    float4 na;
    na.x = pa.x + wk * kv.x; na.y = pa.y + wk * kv.y;
    na.z = pa.z + wk * kv.z; na.w = pa.w + wk * kv.w;
    *reinterpret_cast<float4*>(acc_out + o4) = na;
    float4 sa;
    if (stage < 4) {
      sa.x = ya.x + cst * kv.x; sa.y = ya.y + cst * kv.y;
      sa.z = ya.z + cst * kv.z; sa.w = ya.w + cst * kv.w;
    } else sa = na;
    uint2 pk;
    pk.x = pack2(sa.x, sa.y);
    pk.y = pack2(sa.z, sa.w);
    *reinterpret_cast<uint2*>(ybf + ((size_t)(nodebase + nl4) * 32 + f0 / 2)) = pk;
  }
}

// ---------------------------------------------------------------------------
extern "C" void kernel_launch(void* const* d_in, const int* in_sizes, int n_in,
                              void* d_out, int out_size, void* d_ws, size_t ws_size,
                              hipStream_t stream) {
  const float* y0 = (const float*)d_in[0];
  const float* ts = (const float*)d_in[1];
  const float* controls = (const float*)d_in[2];
  const float* W = (const float*)d_in[3];
  const float* bvec = (const float*)d_in[4];
  const int* node_idx = (const int*)d_in[5];
  const int* edge_idx = (const int*)d_in[6];

  const int d = 64;
  const int n = in_sizes[0] / d;         // 20000
  const int T = in_sizes[1];             // 8
  const int nnz = in_sizes[5];           // 320000
  const int m = 5000;                    // num_edges (fixed by setup_inputs)

  char* p = (char*)d_ws;
  auto carve = [&](size_t bytes) {
    char* r = p;
    p += (bytes + 255) & ~(size_t)255;
    return r;
  };
  int* cnt = (int*)carve((size_t)(m + n) * 4);   // cnt_e | cnt_n contiguous
  int* cnt_e = cnt;
  int* cnt_n = cnt + m;
  int* off_e = (int*)carve((size_t)(m + 1) * 4);
  int* cur_e = (int*)carve((size_t)m * 4);
  int* off_n = (int*)carve((size_t)(n + 1) * 4);
  int* cur_n = (int*)carve((size_t)n * 4);
  int* csr_e = (int*)carve((size_t)nnz * 4);
  int* csr_n = (int*)carve((size_t)nnz * 4);
  float* invdeg_e = (float*)carve((size_t)m * 4);
  float* invdeg_n = (float*)carve((size_t)n * 4);
  ushort* Wt = (ushort*)carve((size_t)512 * 64 * 2);
  ushort* ybf = (ushort*)carve((size_t)n * d * 2);
  ushort* e_bf = (ushort*)carve((size_t)m * d * 2);
  float* y_mid = (float*)carve((size_t)n * d * 4);

  float* out = (float*)d_out;

  hipMemsetAsync(cnt, 0, (size_t)(m + n) * 4, stream);
  k_count<<<(nnz + 255) / 256, 256, 0, stream>>>(node_idx, edge_idx, cnt_e, cnt_n,
                                                 nnz, W, y0, Wt, ybf, out,
                                                 64 * 512, n * d);
  k_scan2<<<2, 1024, 0, stream>>>(cnt_e, off_e, cur_e, m, cnt_n, off_n, cur_n, n);
  k_fill<<<(nnz + 255) / 256, 256, 0, stream>>>(node_idx, edge_idx, cur_e, cur_n,
                                                csr_e, csr_n, nnz, cnt_e, cnt_n,
                                                invdeg_e, invdeg_n, m, n);

  const int gE = (m * 64 + 255) / 256;   // 1250
  const int gT = n / 16;                 // 1250 (n = 20000)

  for (int t = 0; t < T - 1; ++t) {
    float* yout_i = out + (size_t)(t + 1) * n * d;
    for (int sub = 0; sub < 2; ++sub) {
      const float* yb = (sub == 0) ? (out + (size_t)t * n * d) : y_mid;
      float* accp = (sub == 0) ? y_mid : yout_i;
      for (int st = 1; st <= 4; ++st) {
        k_seg_mean_bf<<<gE, 256, 0, stream>>>((const uint*)ybf, off_e, csr_e,
                                              invdeg_e, (uint*)e_bf, m);
        k_drift_f<<<gT, 1024, 0, stream>>>((const uint*)e_bf, off_n, csr_n,
                                           invdeg_n, Wt, bvec, controls, ts,
                                           yb, accp, (uint*)ybf, t, st, sub, n);
      }
    }
  }
}

// Round 11
// 1968.273 us; speedup vs baseline: 1.0535x; 1.0066x over previous
//
#include <hip/hip_runtime.h>

// ---------------------------------------------------------------------------
// HypergraphNeuralCDE: y' = tanh(conv(y)) . dX/dt, RK4 (2 substeps/interval)
// Round 10: (a) fast prefix-scan (per-thread chunks, one block-scan pass);
// (b) k_drift_f hoists ONLY the epilogue y/acc float4 loads above the gather
// (round-7 retry, targeted: +8 VGPR stays under the 64-VGPR (1024,8) cap).
// ---------------------------------------------------------------------------

typedef __attribute__((ext_vector_type(8))) short bfrag8;   // 8 bf16
typedef __attribute__((ext_vector_type(4))) float f32x4;

__device__ __forceinline__ float bf2f(ushort u) {
  union { uint i; float f; } v; v.i = (uint)u << 16; return v.f;
}
__device__ __forceinline__ ushort f2bf(float f) {
  union { uint i; float f; } v; v.f = f;
  uint r = v.i + 0x7fff + ((v.i >> 16) & 1);   // RNE
  return (ushort)(r >> 16);
}
__device__ __forceinline__ uint pack2(float lo, float hi) {
  return ((uint)f2bf(hi) << 16) | (uint)f2bf(lo);
}

// ---------------- CSR construction + one-time prep --------------------------
__global__ __launch_bounds__(256) void k_count(const int* __restrict__ node_idx,
                                               const int* __restrict__ edge_idx,
                                               int* __restrict__ cnt_e,
                                               int* __restrict__ cnt_n, int nnz,
                                               const float* __restrict__ W,
                                               const float* __restrict__ y0,
                                               ushort* __restrict__ Wt,
                                               ushort* __restrict__ y0bf,
                                               float* __restrict__ out,
                                               int nW, int nY) {
  int j = blockIdx.x * 256 + threadIdx.x;
  if (j < nnz) {
    atomicAdd(&cnt_e[edge_idx[j]], 1);
    atomicAdd(&cnt_n[node_idx[j]], 1);
  }
  int stride = gridDim.x * 256;
  for (int i = j; i < nY; i += stride) {
    float v = y0[i];
    y0bf[i] = f2bf(v);
    out[i] = v;                            // out[0] = y0 (folded copy)
  }
  for (int i = j; i < nW; i += stride) {
    int k = i >> 9, c = i & 511;           // W is (64,512) row-major
    Wt[c * 64 + k] = f2bf(W[i]);
  }
}

// fast two-level scan: per-thread sequential chunk + one 1024-wide block scan
// block 0 -> edges, block 1 -> nodes
__global__ __launch_bounds__(1024) void k_scan2(const int* __restrict__ cnt_e,
                                                int* __restrict__ off_e,
                                                int* __restrict__ cur_e, int m,
                                                const int* __restrict__ cnt_n,
                                                int* __restrict__ off_n,
                                                int* __restrict__ cur_n, int n) {
  const int* cnt = (blockIdx.x == 0) ? cnt_e : cnt_n;
  int* off = (blockIdx.x == 0) ? off_e : off_n;
  int* cur = (blockIdx.x == 0) ? cur_e : cur_n;
  int len = (blockIdx.x == 0) ? m : n;
  __shared__ int sd[1024];
  int c = (len + 1023) >> 10;
  int start = threadIdx.x * c;
  int end = start + c;
  if (start > len) start = len;
  if (end > len) end = len;
  int sum = 0;
  for (int i = start; i < end; ++i) sum += cnt[i];
  sd[threadIdx.x] = sum;
  __syncthreads();
  for (int ofs = 1; ofs < 1024; ofs <<= 1) {
    int tv = (threadIdx.x >= ofs) ? sd[threadIdx.x - ofs] : 0;
    __syncthreads();
    sd[threadIdx.x] += tv;
    __syncthreads();
  }
  int run = sd[threadIdx.x] - sum;     // exclusive prefix of this chunk
  for (int i = start; i < end; ++i) {
    off[i] = run;
    cur[i] = run;
    run += cnt[i];
  }
  if (threadIdx.x == 1023) off[len] = sd[1023];
}

// fill + invdeg folded
__global__ __launch_bounds__(256) void k_fill(const int* __restrict__ node_idx,
                                              const int* __restrict__ edge_idx,
                                              int* __restrict__ cur_e,
                                              int* __restrict__ cur_n,
                                              int* __restrict__ csr_e,
                                              int* __restrict__ csr_n, int nnz,
                                              const int* __restrict__ cnt_e,
                                              const int* __restrict__ cnt_n,
                                              float* __restrict__ inv_e,
                                              float* __restrict__ inv_n,
                                              int m, int n) {
  int j = blockIdx.x * 256 + threadIdx.x;
  if (j < nnz) {
    int v = node_idx[j], e = edge_idx[j];
    int pe = atomicAdd(&cur_e[e], 1);
    csr_e[pe] = v;
    int pn = atomicAdd(&cur_n[v], 1);
    csr_n[pn] = e;
  }
  if (j < m) inv_e[j] = 1.f / (float)max(cnt_e[j], 1);
  if (j < n) inv_n[j] = 1.f / (float)max(cnt_n[j], 1);
}

// ---------------- wave-uniform shfl-staged segment accumulate ---------------
__device__ __forceinline__ void seg_gather(const uint* __restrict__ src,
                                           const int* __restrict__ csr,
                                           int p0, int pe, int lane,
                                           float& A0, float& A1) {
  const int half = lane >> 5;
  const int cp = lane & 31;
  const int nent = pe - p0;
  float a0 = 0.f, a1 = 0.f, b0 = 0.f, b1 = 0.f;
  for (int base = 0; base < nent; base += 64) {
    int cnt = nent - base;
    cnt = (cnt > 64) ? 64 : cnt;
    int myidx = (lane < cnt) ? csr[p0 + base + lane] : 0;
    int j = 0;
    // full blocks: entries half+2j .. half+2j+14 valid for BOTH halves
    for (; 2 * j + 15 < cnt; j += 8) {
      int e = half + 2 * j;
      int r0 = __shfl(myidx, e);
      int r1 = __shfl(myidx, e + 2);
      int r2 = __shfl(myidx, e + 4);
      int r3 = __shfl(myidx, e + 6);
      int r4 = __shfl(myidx, e + 8);
      int r5 = __shfl(myidx, e + 10);
      int r6 = __shfl(myidx, e + 12);
      int r7 = __shfl(myidx, e + 14);
      uint v0 = src[(size_t)r0 * 32 + cp];
      uint v1 = src[(size_t)r1 * 32 + cp];
      uint v2 = src[(size_t)r2 * 32 + cp];
      uint v3 = src[(size_t)r3 * 32 + cp];
      uint v4 = src[(size_t)r4 * 32 + cp];
      uint v5 = src[(size_t)r5 * 32 + cp];
      uint v6 = src[(size_t)r6 * 32 + cp];
      uint v7 = src[(size_t)r7 * 32 + cp];
      a0 += bf2f((ushort)(v0 & 0xffff)) + bf2f((ushort)(v2 & 0xffff))
          + bf2f((ushort)(v4 & 0xffff)) + bf2f((ushort)(v6 & 0xffff));
      a1 += bf2f((ushort)(v0 >> 16)) + bf2f((ushort)(v2 >> 16))
          + bf2f((ushort)(v4 >> 16)) + bf2f((ushort)(v6 >> 16));
      b0 += bf2f((ushort)(v1 & 0xffff)) + bf2f((ushort)(v3 & 0xffff))
          + bf2f((ushort)(v5 & 0xffff)) + bf2f((ushort)(v7 & 0xffff));
      b1 += bf2f((ushort)(v1 >> 16)) + bf2f((ushort)(v3 >> 16))
          + bf2f((ushort)(v5 >> 16)) + bf2f((ushort)(v7 >> 16));
    }
    // predicated tail (<=8 iters), wave-uniform bound: 2j < cnt
    for (; 2 * j < cnt; ++j) {
      int e = half + 2 * j;
      int es = (e < 63) ? e : 63;        // clamp shfl source into [0,63]
      int r = __shfl(myidx, es);         // uniform program point, all active
      if (e < cnt) {                     // divergence only around the load
        uint v = src[(size_t)r * 32 + cp];
        a0 += bf2f((ushort)(v & 0xffff));
        a1 += bf2f((ushort)(v >> 16));
      }
    }
  }
  A0 = a0 + b0;
  A1 = a1 + b1;
}

// ---------------- K1: edge mean, bf16 in/out --------------------------------
__global__ __launch_bounds__(256) void k_seg_mean_bf(const uint* __restrict__ src,
                                                     const int* __restrict__ off,
                                                     const int* __restrict__ csr,
                                                     const float* __restrict__ invdeg,
                                                     uint* __restrict__ dst,
                                                     int nseg) {
  int gid = blockIdx.x * 256 + threadIdx.x;
  int seg = gid >> 6;
  if (seg >= nseg) return;
  int lane = gid & 63;
  float sc = invdeg[seg];
  float a0, a1;
  seg_gather(src, csr, off[seg], off[seg + 1], lane, a0, a1);
  a0 += __shfl_xor(a0, 32);
  a1 += __shfl_xor(a1, 32);
  if ((lane >> 5) == 0)
    dst[(size_t)seg * 32 + (lane & 31)] = pack2(a0 * sc, a1 * sc);
}

// ---------------- K2: fused node-mean + MFMA + tanh/contract + RK4 ----------
// 16-node tile, 1024 threads = 16 waves; wave w gathers node nodebase+w and
// covers raw cols [32w, 32w+32). Epilogue y/acc float4s prefetched BEFORE the
// gather (only +8 VGPR for waves 0-3; B-fragments intentionally NOT hoisted).
__global__ __launch_bounds__(1024, 8) void k_drift_f(
    const uint* __restrict__ e_bf,
    const int* __restrict__ off_n, const int* __restrict__ csr_n,
    const float* __restrict__ invdeg_n,
    const ushort* __restrict__ Wt, const float* __restrict__ bvec,
    const float* __restrict__ controls, const float* __restrict__ ts,
    const float* __restrict__ y_base, float* __restrict__ acc_out,
    uint* __restrict__ ybf,
    int t, int stage, int substep, int n) {
  __shared__ uint aggs[16][36];   // row stride 144 B (16B-aligned)
  __shared__ float Us[16][8];
  __shared__ float kvs[16][68];

  const int tid = threadIdx.x;
  const int w = tid >> 6;        // wave 0..15
  const int lane = tid & 63;
  const int cp = lane & 31;
  const int nodebase = blockIdx.x * 16;

  // --- scalar time coefficients (uniform -> SGPR) ---
  float t0v = ts[t], t1v = ts[t + 1];
  float h = t1v - t0v;
  float hs = 0.5f * h;
  float soff = (stage == 1) ? 0.f : (stage == 4) ? 1.f : 0.5f;
  float s = ((float)substep + soff) * 0.5f;
  float s2 = s * s;
  float cx0 = (6.f * s2 - 6.f * s) / h;
  float cd0 = 3.f * s2 - 4.f * s + 1.f;
  float cx1 = (-6.f * s2 + 6.f * s) / h;
  float cd1 = 3.f * s2 - 2.f * s;
  float a_m1, a_0, a_p1;
  if (t == 0) {
    a_m1 = 0.f;
    a_0 = cx0 - cd1 / h - cd0 / h;
    a_p1 = cx1 + cd1 / h + cd0 / h;
  } else {
    float hm = t0v - ts[t - 1];
    a_m1 = -cd0 / hm;
    a_0 = cx0 - cd1 / h + cd0 / hm;
    a_p1 = cx1 + cd1 / h;
  }
  int tm1 = (t > 0) ? t - 1 : 0;
  float wk = ((stage == 2 || stage == 3) ? 2.f : 1.f) * hs * (1.f / 6.f);
  float cst = (stage == 3) ? hs : 0.5f * hs;

  // --- epilogue operand prefetch (threads < 256 only; hides HBM latency
  //     under the gather; round-7 lesson: do NOT also hoist B-fragments) ---
  const int nl4 = tid >> 4;
  const int f0 = (tid & 15) * 4;
  const size_t o4 = (size_t)(nodebase + nl4) * 64 + f0;
  float4 ya = make_float4(0.f, 0.f, 0.f, 0.f);
  float4 pa = ya;
  if (tid < 256) {
    ya = *reinterpret_cast<const float4*>(y_base + o4);
    pa = (stage == 1) ? ya : *reinterpret_cast<const float4*>(acc_out + o4);
  }

  // --- control derivative for the tile's 16 nodes (first 128 threads) ---
  if (tid < 128) {
    int nl = tid >> 3, ci = tid & 7;
    size_t bi = (size_t)(nodebase + nl) * 8 + ci;
    float c0 = controls[(size_t)t * n * 8 + bi];
    float cp1 = controls[(size_t)(t + 1) * n * 8 + bi];
    float cm1 = controls[(size_t)tm1 * n * 8 + bi];
    Us[nl][ci] = a_m1 * cm1 + a_0 * c0 + a_p1 * cp1;
  }

  // --- node-hop gather: wave w -> node nodebase + w ---
  {
    int gnode = nodebase + w;
    float sc = invdeg_n[gnode];
    float a0, a1;
    seg_gather(e_bf, csr_n, off_n[gnode], off_n[gnode + 1], lane, a0, a1);
    a0 += __shfl_xor(a0, 32);
    a1 += __shfl_xor(a1, 32);
    if ((lane >> 5) == 0) aggs[w][cp] = pack2(a0 * sc, a1 * sc);
  }
  __syncthreads();

  // --- MFMA: wave w covers raw cols [32w, 32w+32) ---
  int arow = lane & 15;
  int kof4 = (lane >> 4) * 4;    // uint offset into aggs row
  bfrag8 af0 = *reinterpret_cast<const bfrag8*>(&aggs[arow][kof4]);
  bfrag8 af1 = *reinterpret_cast<const bfrag8*>(&aggs[arow][kof4 + 16]);
  int ci = lane & 7, g8 = (lane >> 3) & 1;
  int rbase = (lane >> 4) * 4;
  float u_r[4];
  #pragma unroll
  for (int r = 0; r < 4; ++r) u_r[r] = Us[rbase + r][ci];

  #pragma unroll
  for (int ctl = 0; ctl < 2; ++ctl) {
    int col = w * 32 + ctl * 16 + (lane & 15);
    const ushort* wb = Wt + (size_t)col * 64 + (lane >> 4) * 8;
    bfrag8 b0 = *reinterpret_cast<const bfrag8*>(wb);
    bfrag8 b1 = *reinterpret_cast<const bfrag8*>(wb + 32);
    f32x4 acc = (f32x4){0.f, 0.f, 0.f, 0.f};
    acc = __builtin_amdgcn_mfma_f32_16x16x32_bf16(af0, b0, acc, 0, 0, 0);
    acc = __builtin_amdgcn_mfma_f32_16x16x32_bf16(af1, b1, acc, 0, 0, 0);
    float bb = bvec[col];
    int ddl = w * 4 + ctl * 2 + g8;
    #pragma unroll
    for (int r = 0; r < 4; ++r) {
      float x = acc[r] + bb;
      float th = 1.f - 2.f / (__expf(2.f * x) + 1.f);  // tanh, NaN-safe
      float v = th * u_r[r];
      v += __shfl_xor(v, 1);
      v += __shfl_xor(v, 2);
      v += __shfl_xor(v, 4);
      if (ci == 0) kvs[rbase + r][ddl] = v;
    }
  }
  __syncthreads();

  // --- RK4 update: first 256 threads (operands prefetched) ---
  if (tid < 256) {
    float4 kv = *reinterpret_cast<float4*>(&kvs[nl4][f0]);
    float4 na;
    na.x = pa.x + wk * kv.x; na.y = pa.y + wk * kv.y;
    na.z = pa.z + wk * kv.z; na.w = pa.w + wk * kv.w;
    *reinterpret_cast<float4*>(acc_out + o4) = na;
    float4 sa;
    if (stage < 4) {
      sa.x = ya.x + cst * kv.x; sa.y = ya.y + cst * kv.y;
      sa.z = ya.z + cst * kv.z; sa.w = ya.w + cst * kv.w;
    } else sa = na;
    uint2 pk;
    pk.x = pack2(sa.x, sa.y);
    pk.y = pack2(sa.z, sa.w);
    *reinterpret_cast<uint2*>(ybf + ((size_t)(nodebase + nl4) * 32 + f0 / 2)) = pk;
  }
}

// ---------------------------------------------------------------------------
extern "C" void kernel_launch(void* const* d_in, const int* in_sizes, int n_in,
                              void* d_out, int out_size, void* d_ws, size_t ws_size,
                              hipStream_t stream) {
  const float* y0 = (const float*)d_in[0];
  const float* ts = (const float*)d_in[1];
  const float* controls = (const float*)d_in[2];
  const float* W = (const float*)d_in[3];
  const float* bvec = (const float*)d_in[4];
  const int* node_idx = (const int*)d_in[5];
  const int* edge_idx = (const int*)d_in[6];

  const int d = 64;
  const int n = in_sizes[0] / d;         // 20000
  const int T = in_sizes[1];             // 8
  const int nnz = in_sizes[5];           // 320000
  const int m = 5000;                    // num_edges (fixed by setup_inputs)

  char* p = (char*)d_ws;
  auto carve = [&](size_t bytes) {
    char* r = p;
    p += (bytes + 255) & ~(size_t)255;
    return r;
  };
  int* cnt = (int*)carve((size_t)(m + n) * 4);   // cnt_e | cnt_n contiguous
  int* cnt_e = cnt;
  int* cnt_n = cnt + m;
  int* off_e = (int*)carve((size_t)(m + 1) * 4);
  int* cur_e = (int*)carve((size_t)m * 4);
  int* off_n = (int*)carve((size_t)(n + 1) * 4);
  int* cur_n = (int*)carve((size_t)n * 4);
  int* csr_e = (int*)carve((size_t)nnz * 4);
  int* csr_n = (int*)carve((size_t)nnz * 4);
  float* invdeg_e = (float*)carve((size_t)m * 4);
  float* invdeg_n = (float*)carve((size_t)n * 4);
  ushort* Wt = (ushort*)carve((size_t)512 * 64 * 2);
  ushort* ybf = (ushort*)carve((size_t)n * d * 2);
  ushort* e_bf = (ushort*)carve((size_t)m * d * 2);
  float* y_mid = (float*)carve((size_t)n * d * 4);

  float* out = (float*)d_out;

  hipMemsetAsync(cnt, 0, (size_t)(m + n) * 4, stream);
  k_count<<<(nnz + 255) / 256, 256, 0, stream>>>(node_idx, edge_idx, cnt_e, cnt_n,
                                                 nnz, W, y0, Wt, ybf, out,
                                                 64 * 512, n * d);
  k_scan2<<<2, 1024, 0, stream>>>(cnt_e, off_e, cur_e, m, cnt_n, off_n, cur_n, n);
  k_fill<<<(nnz + 255) / 256, 256, 0, stream>>>(node_idx, edge_idx, cur_e, cur_n,
                                                csr_e, csr_n, nnz, cnt_e, cnt_n,
                                                invdeg_e, invdeg_n, m, n);

  const int gE = (m * 64 + 255) / 256;   // 1250
  const int gT = n / 16;                 // 1250 (n = 20000)

  for (int t = 0; t < T - 1; ++t) {
    float* yout_i = out + (size_t)(t + 1) * n * d;
    for (int sub = 0; sub < 2; ++sub) {
      const float* yb = (sub == 0) ? (out + (size_t)t * n * d) : y_mid;
      float* accp = (sub == 0) ? y_mid : yout_i;
      for (int st = 1; st <= 4; ++st) {
        k_seg_mean_bf<<<gE, 256, 0, stream>>>((const uint*)ybf, off_e, csr_e,
                                              invdeg_e, (uint*)e_bf, m);
        k_drift_f<<<gT, 1024, 0, stream>>>((const uint*)e_bf, off_n, csr_n,
                                           invdeg_n, Wt, bvec, controls, ts,
                                           yb, accp, (uint*)ybf, t, st, sub, n);
      }
    }
  }
}